// Round 1
// baseline (22997.450 us; speedup 1.0000x reference)
//
#include <hip/hip_runtime.h>
#include <math.h>

#define BATCH 1024
#define DIM   256
#define NCL   50000
#define TOTC  100000   // 2*NC

#define CB  128   // clusters per block
#define MBT 128   // batch rows per tile
#define KT  64    // K chunk staged in LDS

// ---------------------------------------------------------------------------
// Kernel 1: row-normalize inputs, compute the two target logits per row,
// zero the sumexp accumulators. One wave (64 threads) per batch row.
// ---------------------------------------------------------------------------
__global__ __launch_bounds__(64) void k_prep(const float* __restrict__ in,
                                             const int* __restrict__ tgt,
                                             const float* __restrict__ feats,
                                             float* __restrict__ xn,
                                             float* __restrict__ S,
                                             float* __restrict__ z) {
    const int b = blockIdx.x;
    const int t = threadIdx.x;           // 0..63, 4 floats each
    float4 v = *(const float4*)&in[b * DIM + t * 4];
    float ss = v.x * v.x + v.y * v.y + v.z * v.z + v.w * v.w;
#pragma unroll
    for (int o = 1; o < 64; o <<= 1) ss += __shfl_xor(ss, o, 64);
    const float sc = 1.0f / sqrtf(ss);
    float4 w;
    w.x = v.x * sc; w.y = v.y * sc; w.z = v.z * sc; w.w = v.w * sc;
    *(float4*)&xn[b * DIM + t * 4] = w;

    const int tb = tgt[b];
#pragma unroll
    for (int h = 0; h < 2; ++h) {
        const int row = tb + h * NCL;    // mean half = rows [0,NC), hard = [NC,2NC)
        float4 f = *(const float4*)&feats[row * DIM + t * 4];
        float d = w.x * f.x + w.y * f.y + w.z * f.z + w.w * f.w;
#pragma unroll
        for (int o = 1; o < 64; o <<= 1) d += __shfl_xor(d, o, 64);
        if (t == 0) z[b * 2 + h] = d * 20.0f;
    }
    if (t < 2) S[b * 2 + t] = 0.0f;
}

// ---------------------------------------------------------------------------
// Kernel 2: fused GEMM + online sumexp.
// Grid: ceil(100000/128) = 782 blocks; block owns 128 clusters, loops over
// all 8 batch tiles of 128 rows. Features are read exactly once from HBM.
// 256 threads as 16x16; each thread computes an 8x8 micro-tile.
// LDS tiles are XOR-swizzled (k4 ^= (row>>3)&7) so fragment reads are
// conflict-free / 2-way (free).
// ---------------------------------------------------------------------------
__global__ __launch_bounds__(256, 2) void k_main(const float* __restrict__ xn,
                                                 const float* __restrict__ feats,
                                                 float* __restrict__ S) {
    __shared__ float As[MBT * KT];   // 32 KB
    __shared__ float Bs[CB * KT];    // 32 KB
    const int tid = threadIdx.x;
    const int tx = tid & 15;          // col group: cols tx*8 .. tx*8+7
    const int ty = tid >> 4;          // row group: rows ty*8 .. ty*8+7
    const int cb0 = blockIdx.x * CB;

    for (int mb = 0; mb < BATCH; mb += MBT) {
        float acc[8][8];
#pragma unroll
        for (int i = 0; i < 8; ++i)
#pragma unroll
            for (int j = 0; j < 8; ++j) acc[i][j] = 0.0f;

        for (int kt = 0; kt < DIM; kt += KT) {
            // ---- stage A (xn rows) and B (feature rows), 8 float4 each ----
#pragma unroll
            for (int i = 0; i < 8; ++i) {
                const int f4 = tid + i * 256;
                const int r  = f4 >> 4;        // 0..127
                const int k4 = f4 & 15;        // 0..15
                const int k4s = k4 ^ ((r >> 3) & 7);
                float4 av = *(const float4*)&xn[(mb + r) * DIM + kt + k4 * 4];
                *(float4*)&As[r * KT + k4s * 4] = av;
                const int c  = cb0 + r;
                const int cc = c < TOTC ? c : TOTC - 1;   // clamp (masked later)
                float4 bv = *(const float4*)&feats[cc * DIM + kt + k4 * 4];
                *(float4*)&Bs[r * KT + k4s * 4] = bv;
            }
            __syncthreads();

            // ---- compute: 16 k4-steps x (8 A-frag + 8 B-frag b128 reads, 256 FMA)
#pragma unroll
            for (int k4 = 0; k4 < 16; ++k4) {
                float4 a[8];
#pragma unroll
                for (int i = 0; i < 8; ++i) {
                    const int r = ty * 8 + i;
                    a[i] = *(const float4*)&As[r * KT + (k4 ^ ((r >> 3) & 7)) * 4];
                }
#pragma unroll
                for (int j = 0; j < 8; ++j) {
                    const int cl = tx * 8 + j;
                    float4 bb = *(const float4*)&Bs[cl * KT + (k4 ^ ((cl >> 3) & 7)) * 4];
#pragma unroll
                    for (int i = 0; i < 8; ++i) {
                        acc[i][j] += a[i].x * bb.x + a[i].y * bb.y +
                                     a[i].z * bb.z + a[i].w * bb.w;
                    }
                }
            }
            __syncthreads();
        }

        // ---- epilogue: logit = 20*dot, fixed-shift exp, per-row reduce ----
#pragma unroll
        for (int i = 0; i < 8; ++i) {
            const int rg = mb + ty * 8 + i;
            float s0 = 0.0f, s1 = 0.0f;
#pragma unroll
            for (int j = 0; j < 8; ++j) {
                const int c = cb0 + tx * 8 + j;
                const float e = __expf(20.0f * (acc[i][j] - 1.0f)); // exp(logit-20)
                if (c < NCL)        s0 += e;   // mean half
                else if (c < TOTC)  s1 += e;   // hard half
            }
            // reduce across the 16 tx lanes (contiguous within the wave)
#pragma unroll
            for (int o = 1; o < 16; o <<= 1) {
                s0 += __shfl_xor(s0, o, 64);
                s1 += __shfl_xor(s1, o, 64);
            }
            if (tx == 0) {
                atomicAdd(&S[rg * 2 + 0], s0);
                atomicAdd(&S[rg * 2 + 1], s1);
            }
        }
    }
}

// ---------------------------------------------------------------------------
// Kernel 3: loss = 0.5 * mean_b[(20+log S0 - z0) + (20+log S1 - z1)]
// ---------------------------------------------------------------------------
__global__ __launch_bounds__(256) void k_loss(const float* __restrict__ S,
                                              const float* __restrict__ z,
                                              float* __restrict__ out) {
    const int t = threadIdx.x;
    float part = 0.0f;
    for (int r = t; r < BATCH; r += 256) {
        part += 40.0f + logf(S[r * 2 + 0]) + logf(S[r * 2 + 1])
              - z[r * 2 + 0] - z[r * 2 + 1];
    }
#pragma unroll
    for (int o = 1; o < 64; o <<= 1) part += __shfl_xor(part, o, 64);
    __shared__ float ws[4];
    if ((t & 63) == 0) ws[t >> 6] = part;
    __syncthreads();
    if (t == 0) {
        const float tot = ws[0] + ws[1] + ws[2] + ws[3];
        out[0] = 0.5f * tot / (float)BATCH;
    }
}

// ---------------------------------------------------------------------------
extern "C" void kernel_launch(void* const* d_in, const int* in_sizes, int n_in,
                              void* d_out, int out_size, void* d_ws, size_t ws_size,
                              hipStream_t stream) {
    const float* inputs  = (const float*)d_in[0];
    const int*   targets = (const int*)d_in[1];
    const float* feats   = (const float*)d_in[2];
    float* out = (float*)d_out;

    float* xn = (float*)d_ws;              // 1024*256 f32 = 1 MB
    float* S  = xn + BATCH * DIM;          // 1024*2
    float* z  = S + BATCH * 2;             // 1024*2

    k_prep<<<BATCH, 64, 0, stream>>>(inputs, targets, feats, xn, S, z);
    const int nblk = (TOTC + CB - 1) / CB;     // 782
    k_main<<<nblk, 256, 0, stream>>>(xn, feats, S);
    k_loss<<<1, 256, 0, stream>>>(S, z, out);
}

// Round 2
// 239.290 us; speedup vs baseline: 96.1071x; 96.1071x over previous
//
#include <hip/hip_runtime.h>
#include <math.h>

#define BATCH 1024
#define DIM   256
#define NCL   50000
#define TOTC  100000   // 2*NC

typedef __attribute__((ext_vector_type(8))) short bf16x8;   // 8 bf16 = 4 VGPR
typedef __attribute__((ext_vector_type(4))) float f32x4;
typedef __attribute__((ext_vector_type(4))) unsigned int u32x4;

__device__ __forceinline__ unsigned short f2bf(float f) {   // RNE f32 -> bf16
    unsigned int u = __float_as_uint(f);
    unsigned int r = (u + 0x7FFFu + ((u >> 16) & 1u)) >> 16;
    return (unsigned short)r;
}

// ---------------------------------------------------------------------------
// Kernel 1: normalize rows -> bf16 xn; target logits (f32); zero S.
// One wave per batch row.
// ---------------------------------------------------------------------------
__global__ __launch_bounds__(64) void k_prep(const float* __restrict__ in,
                                             const int* __restrict__ tgt,
                                             const float* __restrict__ feats,
                                             unsigned short* __restrict__ xnb,
                                             float* __restrict__ S,
                                             float* __restrict__ z) {
    const int b = blockIdx.x;
    const int t = threadIdx.x;           // 0..63, 4 floats each
    float4 v = *(const float4*)&in[b * DIM + t * 4];
    float ss = v.x * v.x + v.y * v.y + v.z * v.z + v.w * v.w;
#pragma unroll
    for (int o = 1; o < 64; o <<= 1) ss += __shfl_xor(ss, o, 64);
    const float sc = 1.0f / sqrtf(ss);
    float4 w;
    w.x = v.x * sc; w.y = v.y * sc; w.z = v.z * sc; w.w = v.w * sc;

    ushort4 hb;
    hb.x = f2bf(w.x); hb.y = f2bf(w.y); hb.z = f2bf(w.z); hb.w = f2bf(w.w);
    *(ushort4*)&xnb[b * DIM + t * 4] = hb;

    const int tb = tgt[b];
#pragma unroll
    for (int h = 0; h < 2; ++h) {
        const int row = tb + h * NCL;    // mean half rows [0,NC), hard [NC,2NC)
        float4 f = *(const float4*)&feats[row * DIM + t * 4];
        float d = w.x * f.x + w.y * f.y + w.z * f.z + w.w * f.w;
#pragma unroll
        for (int o = 1; o < 64; o <<= 1) d += __shfl_xor(d, o, 64);
        if (t == 0) z[b * 2 + h] = d * 20.0f;
    }
    if (t < 2) S[b * 2 + t] = 0.0f;
}

// ---------------------------------------------------------------------------
// Kernel 2: MFMA GEMM + fused sumexp.
// 782 blocks; block owns 128 clusters (B tile staged to LDS ONCE, f32->bf16),
// loops over 8 batch tiles of 128 rows (A staged per tile from bf16 xn).
// 512 threads = 8 waves as 2(M) x 4(N); wave tile 64x32 = 4x2 MFMA frags.
// LDS rows are 512 B -> XOR-swizzle byte ^= (row&7)<<4 (G4) for the
// ds_read_b128 fragment reads.
// ---------------------------------------------------------------------------
__global__ __launch_bounds__(512, 2) void k_main(const unsigned short* __restrict__ xnb,
                                                 const float* __restrict__ feats,
                                                 float* __restrict__ S) {
    __shared__ unsigned short Ab[128 * 256];  // 64 KB, batch tile
    __shared__ unsigned short Bb[128 * 256];  // 64 KB, cluster tile (resident)
    __shared__ float Sx[256];                 // per-tile row sums [128][2]

    const int tid = threadIdx.x;
    const int cb0 = blockIdx.x * 128;

    // ---- stage B once: 128 feature rows, f32 -> bf16, swizzled ----
#pragma unroll
    for (int it = 0; it < 8; ++it) {
        const int id  = it * 512 + tid;
        const int r   = id >> 5;          // 0..127
        const int c16 = id & 31;          // 16B chunk within 512B row
        int row = cb0 + r;
        if (row > TOTC - 1) row = TOTC - 1;          // clamp; masked in epilogue
        const float4 f0 = *(const float4*)&feats[row * DIM + c16 * 8];
        const float4 f1 = *(const float4*)&feats[row * DIM + c16 * 8 + 4];
        u32x4 p;
        p.x = (unsigned int)f2bf(f0.x) | ((unsigned int)f2bf(f0.y) << 16);
        p.y = (unsigned int)f2bf(f0.z) | ((unsigned int)f2bf(f0.w) << 16);
        p.z = (unsigned int)f2bf(f1.x) | ((unsigned int)f2bf(f1.y) << 16);
        p.w = (unsigned int)f2bf(f1.z) | ((unsigned int)f2bf(f1.w) << 16);
        const int byte = r * 512 + ((c16 * 16) ^ ((r & 7) << 4));
        *(u32x4*)((char*)Bb + byte) = p;
    }

    const int lane = tid & 63;
    const int wid  = tid >> 6;        // 0..7
    const int wm   = wid >> 2;        // 0..1  (M offset wm*64)
    const int wn   = wid & 3;         // 0..3  (N offset wn*32)
    const int l15  = lane & 15;
    const int lk   = lane >> 4;       // 0..3

    for (int mbt = 0; mbt < 8; ++mbt) {
        // ---- stage A: 128 batch rows of bf16, swizzled ----
#pragma unroll
        for (int it = 0; it < 8; ++it) {
            const int id  = it * 512 + tid;
            const int r   = id >> 5;
            const int c16 = id & 31;
            const u32x4 a = *(const u32x4*)&xnb[(mbt * 128 + r) * DIM + c16 * 8];
            const int byte = r * 512 + ((c16 * 16) ^ ((r & 7) << 4));
            *(u32x4*)((char*)Ab + byte) = a;
        }
        if (tid < 256) Sx[tid] = 0.0f;
        __syncthreads();

        // ---- MFMA main loop: K = 256 in 8 steps of 32 ----
        f32x4 acc[4][2];
#pragma unroll
        for (int mt = 0; mt < 4; ++mt)
#pragma unroll
            for (int nn = 0; nn < 2; ++nn) acc[mt][nn] = (f32x4)(0.0f);

#pragma unroll
        for (int kk = 0; kk < 8; ++kk) {
            const int kbyte = kk * 64 + lk * 16;
            bf16x8 af[4], bfr[2];
#pragma unroll
            for (int mt = 0; mt < 4; ++mt) {
                const int row = wm * 64 + mt * 16 + l15;
                af[mt] = *(const bf16x8*)((const char*)Ab +
                          row * 512 + (kbyte ^ ((row & 7) << 4)));
            }
#pragma unroll
            for (int nn = 0; nn < 2; ++nn) {
                const int col = wn * 32 + nn * 16 + l15;
                bfr[nn] = *(const bf16x8*)((const char*)Bb +
                           col * 512 + (kbyte ^ ((col & 7) << 4)));
            }
#pragma unroll
            for (int mt = 0; mt < 4; ++mt)
#pragma unroll
                for (int nn = 0; nn < 2; ++nn)
                    acc[mt][nn] = __builtin_amdgcn_mfma_f32_16x16x32_bf16(
                        af[mt], bfr[nn], acc[mt][nn], 0, 0, 0);
        }

        // ---- epilogue: exp(20*d - 20), per-row sums split by half ----
        f32x4 s0[4], s1[4];
#pragma unroll
        for (int mt = 0; mt < 4; ++mt) { s0[mt] = (f32x4)(0.0f); s1[mt] = (f32x4)(0.0f); }

#pragma unroll
        for (int mt = 0; mt < 4; ++mt) {
#pragma unroll
            for (int nn = 0; nn < 2; ++nn) {
                const int cl = cb0 + wn * 32 + nn * 16 + l15;
                const bool ir = cl < TOTC;
                const bool h0 = cl < NCL;
#pragma unroll
                for (int r = 0; r < 4; ++r) {
                    float e = __expf(20.0f * acc[mt][nn][r] - 20.0f);
                    e = ir ? e : 0.0f;
                    s0[mt][r] += h0 ? e : 0.0f;
                    s1[mt][r] += h0 ? 0.0f : e;
                }
            }
        }
        // reduce across the 16 column-lanes (bits 0..3 of lane)
#pragma unroll
        for (int mt = 0; mt < 4; ++mt)
#pragma unroll
            for (int r = 0; r < 4; ++r) {
#pragma unroll
                for (int o = 1; o < 16; o <<= 1) {
                    s0[mt][r] += __shfl_xor(s0[mt][r], o, 64);
                    s1[mt][r] += __shfl_xor(s1[mt][r], o, 64);
                }
            }
        if (l15 == 0) {
            // lane holds sums for rows wm*64 + mt*16 + lk*4 + r
#pragma unroll
            for (int mt = 0; mt < 4; ++mt)
#pragma unroll
                for (int r = 0; r < 4; ++r) {
                    const int row = wm * 64 + mt * 16 + lk * 4 + r;
                    atomicAdd(&Sx[row * 2 + 0], s0[mt][r]);
                    atomicAdd(&Sx[row * 2 + 1], s1[mt][r]);
                }
        }
        __syncthreads();
        if (tid < 256) {
            // Sx[tid] is (row = tid>>1, half = tid&1) for this batch tile
            atomicAdd(&S[(mbt * 128 + (tid >> 1)) * 2 + (tid & 1)], Sx[tid]);
        }
        // next iteration's __syncthreads() (after A-stage) orders the Sx
        // reuse: thread tid re-zeroes only the Sx[tid] it just read, and
        // Ab is only rewritten after this point (no reader until sync1).
    }
}

// ---------------------------------------------------------------------------
// Kernel 3: loss = 0.5 * mean_b[(20+log S0 - z0) + (20+log S1 - z1)]
// ---------------------------------------------------------------------------
__global__ __launch_bounds__(256) void k_loss(const float* __restrict__ S,
                                              const float* __restrict__ z,
                                              float* __restrict__ out) {
    const int t = threadIdx.x;
    float part = 0.0f;
    for (int r = t; r < BATCH; r += 256) {
        part += 40.0f + logf(S[r * 2 + 0]) + logf(S[r * 2 + 1])
              - z[r * 2 + 0] - z[r * 2 + 1];
    }
#pragma unroll
    for (int o = 1; o < 64; o <<= 1) part += __shfl_xor(part, o, 64);
    __shared__ float ws[4];
    if ((t & 63) == 0) ws[t >> 6] = part;
    __syncthreads();
    if (t == 0) {
        const float tot = ws[0] + ws[1] + ws[2] + ws[3];
        out[0] = 0.5f * tot / (float)BATCH;
    }
}

// ---------------------------------------------------------------------------
extern "C" void kernel_launch(void* const* d_in, const int* in_sizes, int n_in,
                              void* d_out, int out_size, void* d_ws, size_t ws_size,
                              hipStream_t stream) {
    const float* inputs  = (const float*)d_in[0];
    const int*   targets = (const int*)d_in[1];
    const float* feats   = (const float*)d_in[2];
    float* out = (float*)d_out;

    unsigned short* xnb = (unsigned short*)d_ws;          // 1024*256 bf16 = 512 KB
    float* S = (float*)(xnb + BATCH * DIM);               // 1024*2 f32
    float* zt = S + BATCH * 2;                            // 1024*2 f32

    k_prep<<<BATCH, 64, 0, stream>>>(inputs, targets, feats, xnb, S, zt);
    const int nblk = (TOTC + 127) / 128;                  // 782
    k_main<<<nblk, 512, 0, stream>>>(xnb, feats, S);
    k_loss<<<1, 256, 0, stream>>>(S, zt, out);
}

// Round 3
// 179.436 us; speedup vs baseline: 128.1655x; 1.3336x over previous
//
#include <hip/hip_runtime.h>
#include <math.h>

#define BATCH 1024
#define DIM   256
#define NCL   50000
#define TOTC  100000   // 2*NC

typedef __attribute__((ext_vector_type(8)))  short bf16x8;   // 8 bf16 = 4 VGPR
typedef __attribute__((ext_vector_type(16))) float f32x16;   // 32x32 acc frag
typedef __attribute__((ext_vector_type(4)))  unsigned int u32x4;

typedef const __attribute__((address_space(1))) unsigned int* gas_u32p;
typedef __attribute__((address_space(3))) unsigned int* las_u32p;

__device__ __forceinline__ unsigned short f2bf(float f) {   // RNE f32 -> bf16
    unsigned int u = __float_as_uint(f);
    return (unsigned short)((u + 0x7FFFu + ((u >> 16) & 1u)) >> 16);
}

// ---------------------------------------------------------------------------
// Kernel 1: normalize rows -> bf16 xn written PRE-SWIZZLED (16B-chunk index
// XOR (row&31)) so k_main can stage it with a linear global_load_lds copy;
// target logits (f32); zero S. One wave per batch row.
// ---------------------------------------------------------------------------
__global__ __launch_bounds__(64) void k_prep(const float* __restrict__ in,
                                             const int* __restrict__ tgt,
                                             const float* __restrict__ feats,
                                             unsigned short* __restrict__ xnb,
                                             float* __restrict__ S,
                                             float* __restrict__ z) {
    const int b = blockIdx.x;
    const int t = threadIdx.x;           // 0..63, 4 floats each
    float4 v = *(const float4*)&in[b * DIM + t * 4];
    float ss = v.x * v.x + v.y * v.y + v.z * v.z + v.w * v.w;
#pragma unroll
    for (int o = 1; o < 64; o <<= 1) ss += __shfl_xor(ss, o, 64);
    const float sc = 1.0f / sqrtf(ss);
    float4 w;
    w.x = v.x * sc; w.y = v.y * sc; w.z = v.z * sc; w.w = v.w * sc;

    // swizzled write: thread t owns 8 bytes at logical chunk (t>>1), half (t&1)
    const int cd = (t >> 1) ^ (b & 31);
    uint2 p;
    p.x = (unsigned int)f2bf(w.x) | ((unsigned int)f2bf(w.y) << 16);
    p.y = (unsigned int)f2bf(w.z) | ((unsigned int)f2bf(w.w) << 16);
    *(uint2*)((char*)xnb + b * 512 + (cd << 4) + (t & 1) * 8) = p;

    const int tb = tgt[b];
#pragma unroll
    for (int h = 0; h < 2; ++h) {
        const int row = tb + h * NCL;    // mean half rows [0,NC), hard [NC,2NC)
        float4 f = *(const float4*)&feats[row * DIM + t * 4];
        float d = w.x * f.x + w.y * f.y + w.z * f.z + w.w * f.w;
#pragma unroll
        for (int o = 1; o < 64; o <<= 1) d += __shfl_xor(d, o, 64);
        if (t == 0) z[b * 2 + h] = d * 20.0f;
    }
    if (t < 2) S[b * 2 + t] = 0.0f;
}

// ---------------------------------------------------------------------------
// Kernel 2: MFMA GEMM + fused sumexp, A-in-registers.
// 782 blocks; block owns 128 clusters. Each wave caches its 64 cluster rows
// (f32 -> bf16) as A fragments in 128 VGPRs, ONCE. Loop over 4 batch tiles
// of 256: async-stage xn tile into LDS (linear copy of pre-swizzled rows),
// 16 K-steps x (2 ds_read_b128 + 4 mfma_32x32x16). Epilogue: clusters are
// C-ROWS, so sum-over-clusters is per-lane reg sum + one shfl_xor(32).
// ---------------------------------------------------------------------------
__global__ __launch_bounds__(512, 2) void k_main(const unsigned short* __restrict__ xnb,
                                                 const float* __restrict__ feats,
                                                 float* __restrict__ S) {
    __shared__ unsigned short Bb[256 * 256];   // 128 KB: batch tile [n][k] swizzled

    const int tid  = threadIdx.x;
    const int lane = tid & 63;
    const int wid  = tid >> 6;        // 0..7
    const int wm   = wid >> 2;        // 0..1  (M offset wm*64)
    const int wn   = wid & 3;         // 0..3  (N offset wn*64)
    const int l31  = lane & 31;
    const int hi   = lane >> 5;       // 0/1
    const int cb0  = blockIdx.x * 128;

    // ---- A cache: 2 M-frags x 16 K-steps; lane holds row (base+l31),
    //      k = kk*16 + hi*8 + j  (j=0..7) ----
    bf16x8 ac[2][16];
#pragma unroll
    for (int mt = 0; mt < 2; ++mt) {
        int row = cb0 + wm * 64 + mt * 32 + l31;
        if (row > TOTC - 1) row = TOTC - 1;        // clamp; masked in epilogue
        const float* rp = &feats[(size_t)row * DIM];
#pragma unroll
        for (int kk = 0; kk < 16; ++kk) {
            const float4 f0 = *(const float4*)&rp[kk * 16 + hi * 8];
            const float4 f1 = *(const float4*)&rp[kk * 16 + hi * 8 + 4];
            bf16x8 a;
            a[0] = (short)f2bf(f0.x); a[1] = (short)f2bf(f0.y);
            a[2] = (short)f2bf(f0.z); a[3] = (short)f2bf(f0.w);
            a[4] = (short)f2bf(f1.x); a[5] = (short)f2bf(f1.y);
            a[6] = (short)f2bf(f1.z); a[7] = (short)f2bf(f1.w);
            ac[mt][kk] = a;
        }
    }

    const bool mixed = (cb0 < NCL && cb0 + 127 >= NCL) || (cb0 + 127 >= TOTC);
    const int  halfsel = (cb0 >= NCL) ? 1 : 0;

    for (int bt = 0; bt < 4; ++bt) {
        // ---- async stage: linear 128 KB copy (source rows pre-swizzled) ----
        const char* srcb = (const char*)xnb + (size_t)bt * 131072;
#pragma unroll
        for (int it = 0; it < 16; ++it) {
            const int seg = it * 8 + wid;               // 1 KB segment per wave
            __builtin_amdgcn_global_load_lds(
                (gas_u32p)(srcb + seg * 1024 + lane * 16),
                (las_u32p)((char*)Bb + seg * 1024),
                16, 0, 0);
        }
        __syncthreads();   // drains vmcnt

        f32x16 acc[2][2];
#pragma unroll
        for (int mt = 0; mt < 2; ++mt)
#pragma unroll
            for (int nn = 0; nn < 2; ++nn) acc[mt][nn] = (f32x16)(0.0f);

#pragma unroll
        for (int kk = 0; kk < 16; ++kk) {
            bf16x8 bf[2];
#pragma unroll
            for (int nn = 0; nn < 2; ++nn) {
                const int row = wn * 64 + nn * 32 + l31;     // batch col in tile
                const int kc  = (kk * 2 + hi) ^ (row & 31);  // swizzled 16B chunk
                bf[nn] = *(const bf16x8*)((const char*)Bb + row * 512 + (kc << 4));
            }
#pragma unroll
            for (int mt = 0; mt < 2; ++mt)
#pragma unroll
                for (int nn = 0; nn < 2; ++nn)
                    acc[mt][nn] = __builtin_amdgcn_mfma_f32_32x32x16_bf16(
                        ac[mt][kk], bf[nn], acc[mt][nn], 0, 0, 0);
        }
        __syncthreads();   // all Bb reads done before next tile's stage

        // ---- epilogue: e = exp(20*d - 20); sum over cluster rows ----
        if (!mixed) {
            float s0 = 0.0f, s1 = 0.0f;
#pragma unroll
            for (int mt = 0; mt < 2; ++mt)
#pragma unroll
                for (int r = 0; r < 16; ++r) {
                    s0 += __expf(fmaf(acc[mt][0][r], 20.0f, -20.0f));
                    s1 += __expf(fmaf(acc[mt][1][r], 20.0f, -20.0f));
                }
            s0 += __shfl_xor(s0, 32, 64);
            s1 += __shfl_xor(s1, 32, 64);
            if (hi == 0) {
                const int b0 = bt * 256 + wn * 64 + l31;
                atomicAdd(&S[b0 * 2 + halfsel], s0);
                atomicAdd(&S[(b0 + 32) * 2 + halfsel], s1);
            }
        } else {
            // boundary blocks (390: NCL split, 781: tail) — per-element masks
            float s00 = 0.0f, s01 = 0.0f, s10 = 0.0f, s11 = 0.0f;
#pragma unroll
            for (int mt = 0; mt < 2; ++mt)
#pragma unroll
                for (int r = 0; r < 16; ++r) {
                    const int cl = cb0 + wm * 64 + mt * 32 +
                                   (r & 3) + 8 * (r >> 2) + 4 * hi;
                    const bool valid = cl < TOTC;
                    const bool h0 = cl < NCL;
                    float e0 = __expf(fmaf(acc[mt][0][r], 20.0f, -20.0f));
                    float e1 = __expf(fmaf(acc[mt][1][r], 20.0f, -20.0f));
                    e0 = valid ? e0 : 0.0f;
                    e1 = valid ? e1 : 0.0f;
                    s00 += h0 ? e0 : 0.0f;  s01 += h0 ? 0.0f : e0;
                    s10 += h0 ? e1 : 0.0f;  s11 += h0 ? 0.0f : e1;
                }
            s00 += __shfl_xor(s00, 32, 64); s01 += __shfl_xor(s01, 32, 64);
            s10 += __shfl_xor(s10, 32, 64); s11 += __shfl_xor(s11, 32, 64);
            if (hi == 0) {
                const int b0 = bt * 256 + wn * 64 + l31;
                atomicAdd(&S[b0 * 2 + 0], s00);
                atomicAdd(&S[b0 * 2 + 1], s01);
                atomicAdd(&S[(b0 + 32) * 2 + 0], s10);
                atomicAdd(&S[(b0 + 32) * 2 + 1], s11);
            }
        }
    }
}

// ---------------------------------------------------------------------------
// Kernel 3: loss = 0.5 * mean_b[(20+log S0 - z0) + (20+log S1 - z1)]
// ---------------------------------------------------------------------------
__global__ __launch_bounds__(256) void k_loss(const float* __restrict__ S,
                                              const float* __restrict__ z,
                                              float* __restrict__ out) {
    const int t = threadIdx.x;
    float part = 0.0f;
    for (int r = t; r < BATCH; r += 256) {
        part += 40.0f + logf(S[r * 2 + 0]) + logf(S[r * 2 + 1])
              - z[r * 2 + 0] - z[r * 2 + 1];
    }
#pragma unroll
    for (int o = 1; o < 64; o <<= 1) part += __shfl_xor(part, o, 64);
    __shared__ float ws[4];
    if ((t & 63) == 0) ws[t >> 6] = part;
    __syncthreads();
    if (t == 0) {
        const float tot = ws[0] + ws[1] + ws[2] + ws[3];
        out[0] = 0.5f * tot / (float)BATCH;
    }
}

// ---------------------------------------------------------------------------
extern "C" void kernel_launch(void* const* d_in, const int* in_sizes, int n_in,
                              void* d_out, int out_size, void* d_ws, size_t ws_size,
                              hipStream_t stream) {
    const float* inputs  = (const float*)d_in[0];
    const int*   targets = (const int*)d_in[1];
    const float* feats   = (const float*)d_in[2];
    float* out = (float*)d_out;

    unsigned short* xnb = (unsigned short*)d_ws;          // 1024*256 bf16 = 512 KB
    float* S  = (float*)(xnb + BATCH * DIM);              // 1024*2 f32
    float* zt = S + BATCH * 2;                            // 1024*2 f32

    k_prep<<<BATCH, 64, 0, stream>>>(inputs, targets, feats, xnb, S, zt);
    const int nblk = (TOTC + 127) / 128;                  // 782
    k_main<<<nblk, 512, 0, stream>>>(xnb, feats, S);
    k_loss<<<1, 256, 0, stream>>>(S, zt, out);
}

// Round 4
// 151.743 us; speedup vs baseline: 151.5555x; 1.1825x over previous
//
#include <hip/hip_runtime.h>
#include <math.h>

#define BATCH 1024
#define DIM   256
#define NCL   50000
#define TOTC  100000   // 2*NC
#define NSLICE 16

typedef __attribute__((ext_vector_type(8)))  short bf16x8;   // 8 bf16 = 4 VGPR
typedef __attribute__((ext_vector_type(16))) float f32x16;   // 32x32 acc frag

typedef const __attribute__((address_space(1))) unsigned int* gas_u32p;
typedef __attribute__((address_space(3))) unsigned int* las_u32p;

__device__ __forceinline__ unsigned short f2bf(float f) {   // RNE f32 -> bf16
    unsigned int u = __float_as_uint(f);
    return (unsigned short)((u + 0x7FFFu + ((u >> 16) & 1u)) >> 16);
}

// ---------------------------------------------------------------------------
// Kernel 1: normalize rows -> bf16 xn written PRE-SWIZZLED (16B-chunk index
// XOR (row&31)) so k_main stages it with a linear global_load_lds copy;
// target logits (f32); zero the sliced accumulators. One wave per batch row.
// ---------------------------------------------------------------------------
__global__ __launch_bounds__(64) void k_prep(const float* __restrict__ in,
                                             const int* __restrict__ tgt,
                                             const float* __restrict__ feats,
                                             unsigned short* __restrict__ xnb,
                                             float* __restrict__ Sx,
                                             float* __restrict__ z) {
    const int b = blockIdx.x;
    const int t = threadIdx.x;           // 0..63, 4 floats each
    float4 v = *(const float4*)&in[b * DIM + t * 4];
    float ss = v.x * v.x + v.y * v.y + v.z * v.z + v.w * v.w;
#pragma unroll
    for (int o = 1; o < 64; o <<= 1) ss += __shfl_xor(ss, o, 64);
    const float sc = 1.0f / sqrtf(ss);
    float4 w;
    w.x = v.x * sc; w.y = v.y * sc; w.z = v.z * sc; w.w = v.w * sc;

    // swizzled write: thread t owns 8 bytes at logical chunk (t>>1), half (t&1)
    const int cd = (t >> 1) ^ (b & 31);
    uint2 p;
    p.x = (unsigned int)f2bf(w.x) | ((unsigned int)f2bf(w.y) << 16);
    p.y = (unsigned int)f2bf(w.z) | ((unsigned int)f2bf(w.w) << 16);
    *(uint2*)((char*)xnb + b * 512 + (cd << 4) + (t & 1) * 8) = p;

    const int tb = tgt[b];
#pragma unroll
    for (int h = 0; h < 2; ++h) {
        const int row = tb + h * NCL;    // mean half rows [0,NC), hard [NC,2NC)
        float4 f = *(const float4*)&feats[row * DIM + t * 4];
        float d = w.x * f.x + w.y * f.y + w.z * f.z + w.w * f.w;
#pragma unroll
        for (int o = 1; o < 64; o <<= 1) d += __shfl_xor(d, o, 64);
        if (t == 0) z[b * 2 + h] = d * 20.0f;
    }
    // zero sliced accumulators: 16*1024*2 = 32768 floats over 1024 blocks
    if (t < 32) Sx[b * 32 + t] = 0.0f;
}

// ---------------------------------------------------------------------------
// Kernel 2: MFMA GEMM + fused sumexp, A-in-registers, 2-phase pipelined LDS.
// 782 blocks; block owns 128 clusters. Each wave caches its 64 cluster rows
// (f32 -> bf16) as MFMA A-frags in 128 VGPRs, ONCE (overlapped with tile-0
// staging). Loop 8 batch tiles of 128: stage(bt+1) issued BEFORE compute(bt),
// counted s_waitcnt vmcnt(8) + raw s_barrier (loads stay in flight across
// the barrier). Epilogue: clusters are C-rows -> per-lane reg sum + one
// shfl_xor(32); atomics go to XCD-local slice S[blockIdx&15].
// ---------------------------------------------------------------------------
__global__ __launch_bounds__(512, 2) void k_main(const unsigned short* __restrict__ xnb,
                                                 const float* __restrict__ feats,
                                                 float* __restrict__ Sx) {
    __shared__ unsigned short Bb[2][128 * 256];   // 2 x 64 KB double buffer

    const int tid  = threadIdx.x;
    const int lane = tid & 63;
    const int wid  = tid >> 6;        // 0..7
    const int wm   = wid >> 2;        // 0..1  (M offset wm*64)
    const int wn   = wid & 3;         // 0..3  (N offset wn*32)
    const int l31  = lane & 31;
    const int hi   = lane >> 5;       // 0/1
    const int cb0  = blockIdx.x * 128;
    float* Ss = Sx + (blockIdx.x & (NSLICE - 1)) * (BATCH * 2);

#define STAGE(bufp, bt_) do {                                              \
        const char* sb_ = (const char*)xnb + (size_t)(bt_) * 65536;        \
        _Pragma("unroll")                                                  \
        for (int i_ = 0; i_ < 8; ++i_) {                                   \
            const int seg_ = wid * 8 + i_;                                 \
            __builtin_amdgcn_global_load_lds(                              \
                (gas_u32p)(sb_ + seg_ * 1024 + lane * 16),                 \
                (las_u32p)((char*)(bufp) + seg_ * 1024), 16, 0, 0);        \
        }                                                                  \
    } while (0)

    // ---- issue tile-0 staging first: it streams in under the A-phase ----
    STAGE(Bb[0], 0);

    // ---- A cache: 2 M-frags x 16 K-steps; lane holds row (base+l31),
    //      k = kk*16 + hi*8 + j ----
    bf16x8 ac[2][16];
#pragma unroll
    for (int mt = 0; mt < 2; ++mt) {
        int row = cb0 + wm * 64 + mt * 32 + l31;
        if (row > TOTC - 1) row = TOTC - 1;        // clamp; masked in epilogue
        const float* rp = &feats[(size_t)row * DIM];
#pragma unroll
        for (int kk = 0; kk < 16; ++kk) {
            const float4 f0 = *(const float4*)&rp[kk * 16 + hi * 8];
            const float4 f1 = *(const float4*)&rp[kk * 16 + hi * 8 + 4];
            bf16x8 a;
            a[0] = (short)f2bf(f0.x); a[1] = (short)f2bf(f0.y);
            a[2] = (short)f2bf(f0.z); a[3] = (short)f2bf(f0.w);
            a[4] = (short)f2bf(f1.x); a[5] = (short)f2bf(f1.y);
            a[6] = (short)f2bf(f1.z); a[7] = (short)f2bf(f1.w);
            ac[mt][kk] = a;
        }
    }

    const bool mixed = (cb0 < NCL && cb0 + 127 >= NCL) || (cb0 + 127 >= TOTC);
    const int  halfsel = (cb0 >= NCL) ? 1 : 0;

    for (int bt = 0; bt < 8; ++bt) {
        const int cur = bt & 1;
        if (bt < 7) {
            STAGE(Bb[cur ^ 1], bt + 1);
            // drain all but the 8 just-issued loads: tile bt's loads AND the
            // previous epilogue's atomics are older -> complete after this.
            asm volatile("s_waitcnt vmcnt(8)" ::: "memory");
        } else {
            asm volatile("s_waitcnt vmcnt(0)" ::: "memory");
        }
        __builtin_amdgcn_sched_barrier(0);
        __builtin_amdgcn_s_barrier();       // raw: no compiler vmcnt(0) drain
        __builtin_amdgcn_sched_barrier(0);

        // ---- compute: K = 256 in 16 steps of 16; 1 ds_read + 2 MFMA/step ----
        f32x16 acc0 = (f32x16)(0.0f), acc1 = (f32x16)(0.0f);
        const char* bb = (const char*)Bb[cur];
#pragma unroll
        for (int kk = 0; kk < 16; ++kk) {
            // batch col (local) = wn*32 + l31; swizzle key = l31
            const int kc = (kk * 2 + hi) ^ l31;
            const bf16x8 bf = *(const bf16x8*)(bb + (wn * 32 + l31) * 512 + (kc << 4));
            acc0 = __builtin_amdgcn_mfma_f32_32x32x16_bf16(ac[0][kk], bf, acc0, 0, 0, 0);
            acc1 = __builtin_amdgcn_mfma_f32_32x32x16_bf16(ac[1][kk], bf, acc1, 0, 0, 0);
        }

        // ---- epilogue: e = exp(20*d - 20); sum over this wave's 64 clusters ----
        const int bcol = bt * 128 + wn * 32 + l31;     // global batch row
        if (!mixed) {
            float s = 0.0f;
#pragma unroll
            for (int r = 0; r < 16; ++r) {
                s += __expf(fmaf(acc0[r], 20.0f, -20.0f));
                s += __expf(fmaf(acc1[r], 20.0f, -20.0f));
            }
            s += __shfl_xor(s, 32, 64);
            if (hi == 0) atomicAdd(&Ss[bcol * 2 + halfsel], s);
        } else {
            float sh0 = 0.0f, sh1 = 0.0f;
#pragma unroll
            for (int mt = 0; mt < 2; ++mt)
#pragma unroll
                for (int r = 0; r < 16; ++r) {
                    const int cl = cb0 + wm * 64 + mt * 32 +
                                   (r & 3) + 8 * (r >> 2) + 4 * hi;
                    const bool valid = cl < TOTC;
                    float e = __expf(fmaf((mt ? acc1[r] : acc0[r]), 20.0f, -20.0f));
                    e = valid ? e : 0.0f;
                    sh0 += (cl < NCL) ? e : 0.0f;
                    sh1 += (cl < NCL) ? 0.0f : e;
                }
            sh0 += __shfl_xor(sh0, 32, 64);
            sh1 += __shfl_xor(sh1, 32, 64);
            if (hi == 0) {
                atomicAdd(&Ss[bcol * 2 + 0], sh0);
                atomicAdd(&Ss[bcol * 2 + 1], sh1);
            }
        }

        __builtin_amdgcn_sched_barrier(0);
        __builtin_amdgcn_s_barrier();       // all reads of Bb[cur] done before
        __builtin_amdgcn_sched_barrier(0);  // next iter overwrites it
    }
#undef STAGE
}

// ---------------------------------------------------------------------------
// Kernel 3: loss = 0.5 * mean_b[(20+log S0 - z0) + (20+log S1 - z1)],
// summing the 16 slices first.
// ---------------------------------------------------------------------------
__global__ __launch_bounds__(256) void k_loss(const float* __restrict__ Sx,
                                              const float* __restrict__ z,
                                              float* __restrict__ out) {
    const int t = threadIdx.x;
    float part = 0.0f;
    for (int r = t; r < BATCH; r += 256) {
        float s0 = 0.0f, s1 = 0.0f;
#pragma unroll
        for (int sl = 0; sl < NSLICE; ++sl) {
            s0 += Sx[sl * (BATCH * 2) + r * 2 + 0];
            s1 += Sx[sl * (BATCH * 2) + r * 2 + 1];
        }
        part += 40.0f + logf(s0) + logf(s1) - z[r * 2 + 0] - z[r * 2 + 1];
    }
#pragma unroll
    for (int o = 1; o < 64; o <<= 1) part += __shfl_xor(part, o, 64);
    __shared__ float ws[4];
    if ((t & 63) == 0) ws[t >> 6] = part;
    __syncthreads();
    if (t == 0) {
        const float tot = ws[0] + ws[1] + ws[2] + ws[3];
        out[0] = 0.5f * tot / (float)BATCH;
    }
}

// ---------------------------------------------------------------------------
extern "C" void kernel_launch(void* const* d_in, const int* in_sizes, int n_in,
                              void* d_out, int out_size, void* d_ws, size_t ws_size,
                              hipStream_t stream) {
    const float* inputs  = (const float*)d_in[0];
    const int*   targets = (const int*)d_in[1];
    const float* feats   = (const float*)d_in[2];
    float* out = (float*)d_out;

    unsigned short* xnb = (unsigned short*)d_ws;          // 1024*256 bf16 = 512 KB
    float* Sx = (float*)(xnb + BATCH * DIM);              // 16*1024*2 f32 = 128 KB
    float* zt = Sx + NSLICE * BATCH * 2;                  // 1024*2 f32

    k_prep<<<BATCH, 64, 0, stream>>>(inputs, targets, feats, xnb, Sx, zt);
    const int nblk = (TOTC + 127) / 128;                  // 782
    k_main<<<nblk, 512, 0, stream>>>(xnb, feats, Sx);
    k_loss<<<1, 256, 0, stream>>>(Sx, zt, out);
}